// Round 1
// baseline (70.380 us; speedup 1.0000x reference)
//
#include <hip/hip_runtime.h>

// Problem constants from the reference: B=64, H=512, W=512.
// depth, masks: [B,H,W] f32; intrinsics: [B,3,3] f32; out: [B,H,W,3] f32.
// Pure elementwise back-projection -> memory-bound. Each thread handles 4
// consecutive pixels: float4 input loads, 3x float4 output stores (coalesced).

#define HW_BITS 18   // H*W = 512*512 = 2^18
#define W_BITS   9   // W = 512 = 2^9

__global__ __launch_bounds__(256) void sam3d_pc_kernel(
    const float* __restrict__ depth,
    const float* __restrict__ masks,
    const float* __restrict__ intr,
    float* __restrict__ out,
    int n_groups)  // total pixel-groups of 4
{
    int tid = blockIdx.x * blockDim.x + threadIdx.x;
    if (tid >= n_groups) return;

    long p = (long)tid << 2;                       // base pixel index (multiple of 4)
    int b   = (int)(p >> HW_BITS);                 // batch
    int rem = (int)(p & ((1 << HW_BITS) - 1));
    float y = (float)(rem >> W_BITS);              // row (uniform across the 4 pixels)
    int x0  = rem & ((1 << W_BITS) - 1);           // first column

    const float* K = intr + b * 9;
    float fx = K[0], cx = K[2], fy = K[4], cy = K[5];
    float inv_fx = 1.0f / fx;
    float inv_fy = 1.0f / fy;
    float ycy = (y - cy) * inv_fy;                 // (y-cy)/fy, uniform per thread

    float4 d4 = *reinterpret_cast<const float4*>(depth + p);
    float4 m4 = *reinterpret_cast<const float4*>(masks + p);

    float o[12];
    const float* dv = &d4.x;
    const float* mv = &m4.x;
    #pragma unroll
    for (int i = 0; i < 4; ++i) {
        float d = dv[i];
        float m = mv[i];
        // finite check via bit pattern (robust to fast-math): exp != all-ones
        unsigned bits = __float_as_uint(d);
        bool finite = (bits & 0x7fffffffu) < 0x7f800000u;
        bool valid = (m > 0.5f) & finite & (d > 0.0f);
        float px = ((float)(x0 + i) - cx) * d * inv_fx;
        float py = ycy * d;
        o[3*i+0] = valid ? px : 0.0f;
        o[3*i+1] = valid ? py : 0.0f;
        o[3*i+2] = valid ? d  : 0.0f;
    }

    float4* ob = reinterpret_cast<float4*>(out + p * 3);  // 48B-aligned
    ob[0] = make_float4(o[0], o[1], o[2],  o[3]);
    ob[1] = make_float4(o[4], o[5], o[6],  o[7]);
    ob[2] = make_float4(o[8], o[9], o[10], o[11]);
}

extern "C" void kernel_launch(void* const* d_in, const int* in_sizes, int n_in,
                              void* d_out, int out_size, void* d_ws, size_t ws_size,
                              hipStream_t stream) {
    const float* depth = (const float*)d_in[0];
    const float* masks = (const float*)d_in[1];
    const float* intr  = (const float*)d_in[2];
    float* out = (float*)d_out;

    const int total_pixels = in_sizes[0];          // B*H*W = 16,777,216
    const int n_groups = total_pixels >> 2;        // 4,194,304
    const int block = 256;
    const int grid = (n_groups + block - 1) / block;

    sam3d_pc_kernel<<<grid, block, 0, stream>>>(depth, masks, intr, out, n_groups);
}

// Round 3
// 63.290 us; speedup vs baseline: 1.1120x; 1.1120x over previous
//
#include <hip/hip_runtime.h>

// B=64, H=512, W=512. depth,masks: [B,H,W] f32; intrinsics: [B,3,3] f32;
// out: [B,H,W,3] f32. Memory-bound elementwise back-projection.
//
// Each thread: 4 consecutive pixels (float4 input loads). Output (12 floats
// per thread, 48 B) is staged through a per-wave LDS slice so the 3 global
// store instructions per wave are each fully contiguous (64 lanes x 16 B =
// 1 KiB dense per instruction) instead of 48-byte-strided.

#define HW_BITS 18   // H*W = 2^18
#define W_BITS   9   // W = 2^9

__global__ __launch_bounds__(256) void sam3d_pc_kernel(
    const float* __restrict__ depth,
    const float* __restrict__ masks,
    const float* __restrict__ intr,
    float* __restrict__ out)
{
    // per-wave staging: 64 lanes * 12 floats = 3072 B per wave, 12 KiB/block.
    __shared__ float lds[4][768];

    const int wave = threadIdx.x >> 6;
    const int lane = threadIdx.x & 63;
    const int tid  = blockIdx.x * 256 + threadIdx.x;

    const int p   = tid << 2;                    // base pixel (multiple of 4)
    const int b   = p >> HW_BITS;
    const int rem = p & ((1 << HW_BITS) - 1);
    const float y = (float)(rem >> W_BITS);
    const int x0  = rem & ((1 << W_BITS) - 1);

    const float* K = intr + b * 9;
    const float cx = K[2], cy = K[5];
    const float inv_fx = 1.0f / K[0];
    const float inv_fy = 1.0f / K[4];
    const float ycy = (y - cy) * inv_fy;         // uniform over the 4 pixels

    const float4 d4 = *reinterpret_cast<const float4*>(depth + p);
    const float4 m4 = *reinterpret_cast<const float4*>(masks + p);

    float o[12];
    const float* dv = &d4.x;
    const float* mv = &m4.x;
    #pragma unroll
    for (int i = 0; i < 4; ++i) {
        const float d = dv[i];
        const float m = mv[i];
        const unsigned bits = __float_as_uint(d);
        const bool finite = (bits & 0x7fffffffu) < 0x7f800000u;  // fast-math-proof
        const bool valid  = (m > 0.5f) & finite & (d > 0.0f);
        const float px = ((float)(x0 + i) - cx) * d * inv_fx;
        const float py = ycy * d;
        o[3*i+0] = valid ? px : 0.0f;
        o[3*i+1] = valid ? py : 0.0f;
        o[3*i+2] = valid ? d  : 0.0f;
    }

    // Stage 12 floats -> LDS (lane*48 B is 16B-aligned; bank-uniform pattern).
    float* wl = &lds[wave][lane * 12];
    reinterpret_cast<float4*>(wl)[0] = make_float4(o[0], o[1], o[2],  o[3]);
    reinterpret_cast<float4*>(wl)[1] = make_float4(o[4], o[5], o[6],  o[7]);
    reinterpret_cast<float4*>(wl)[2] = make_float4(o[8], o[9], o[10], o[11]);

    // Read back contiguous and store fully-coalesced. Wave only touches its
    // own LDS slice -> no __syncthreads needed (within-wave dependency).
    const float4* lv = reinterpret_cast<const float4*>(&lds[wave][0]);
    float4* outv = reinterpret_cast<float4*>(out);
    // Block writes 256 threads * 3 float4 = 768 float4; wave writes 192.
    const long base4 = (long)blockIdx.x * 768 + wave * 192;  // float4 units
    #pragma unroll
    for (int j = 0; j < 3; ++j) {
        outv[base4 + j * 64 + lane] = lv[j * 64 + lane];
    }
}

extern "C" void kernel_launch(void* const* d_in, const int* in_sizes, int n_in,
                              void* d_out, int out_size, void* d_ws, size_t ws_size,
                              hipStream_t stream) {
    const float* depth = (const float*)d_in[0];
    const float* masks = (const float*)d_in[1];
    const float* intr  = (const float*)d_in[2];
    float* out = (float*)d_out;

    const int total_pixels = in_sizes[0];          // 16,777,216
    const int n_groups = total_pixels >> 2;        // 4,194,304 threads
    const int block = 256;
    const int grid = n_groups / block;             // 16,384 (exact)

    sam3d_pc_kernel<<<grid, block, 0, stream>>>(depth, masks, intr, out);
}

// Round 5
// 52.772 us; speedup vs baseline: 1.3337x; 1.1993x over previous
//
#include <hip/hip_runtime.h>

// B=64, H=512, W=512. depth,masks: [B,H,W] f32; intrinsics: [B,3,3] f32;
// out: [B,H,W,3] f32. Memory-bound elementwise back-projection.
//
// Each thread: 4 consecutive pixels (float4 input loads). Output staged
// through a per-wave LDS slice -> 3 fully-contiguous 16B stores per wave.
// Stores are NON-TEMPORAL: output (192 MB) is write-once, so keep it from
// evicting the 128 MB of inputs out of the 256 MB L3 (inputs stay resident
// across graph replays -> reads become L3 hits, kernel becomes write-bound).

#define HW_BITS 18   // H*W = 2^18
#define W_BITS   9   // W = 2^9

// native clang vector: accepted by __builtin_nontemporal_store (HIP's float4
// is a struct and is rejected). Same 16B size/alignment.
typedef float vfloat4 __attribute__((ext_vector_type(4)));

__global__ __launch_bounds__(256) void sam3d_pc_kernel(
    const float* __restrict__ depth,
    const float* __restrict__ masks,
    const float* __restrict__ intr,
    float* __restrict__ out)
{
    // per-wave staging: 64 lanes * 12 floats = 3072 B per wave, 12 KiB/block.
    __shared__ float lds[4][768];

    const int wave = threadIdx.x >> 6;
    const int lane = threadIdx.x & 63;
    const int tid  = blockIdx.x * 256 + threadIdx.x;

    const int p   = tid << 2;                    // base pixel (multiple of 4)
    const int b   = p >> HW_BITS;
    const int rem = p & ((1 << HW_BITS) - 1);
    const float y = (float)(rem >> W_BITS);
    const int x0  = rem & ((1 << W_BITS) - 1);

    const float* K = intr + b * 9;
    const float cx = K[2], cy = K[5];
    const float inv_fx = 1.0f / K[0];
    const float inv_fy = 1.0f / K[4];
    const float ycy = (y - cy) * inv_fy;         // uniform over the 4 pixels

    const vfloat4 d4 = *reinterpret_cast<const vfloat4*>(depth + p);
    const vfloat4 m4 = *reinterpret_cast<const vfloat4*>(masks + p);

    float o[12];
    #pragma unroll
    for (int i = 0; i < 4; ++i) {
        const float d = d4[i];
        const float m = m4[i];
        const unsigned bits = __float_as_uint(d);
        const bool finite = (bits & 0x7fffffffu) < 0x7f800000u;  // fast-math-proof
        const bool valid  = (m > 0.5f) & finite & (d > 0.0f);
        const float px = ((float)(x0 + i) - cx) * d * inv_fx;
        const float py = ycy * d;
        o[3*i+0] = valid ? px : 0.0f;
        o[3*i+1] = valid ? py : 0.0f;
        o[3*i+2] = valid ? d  : 0.0f;
    }

    // Stage 12 floats -> LDS (lane*48 B, 16B-aligned, bank-uniform).
    float* wl = &lds[wave][lane * 12];
    reinterpret_cast<vfloat4*>(wl)[0] = (vfloat4){o[0], o[1], o[2],  o[3]};
    reinterpret_cast<vfloat4*>(wl)[1] = (vfloat4){o[4], o[5], o[6],  o[7]};
    reinterpret_cast<vfloat4*>(wl)[2] = (vfloat4){o[8], o[9], o[10], o[11]};

    // Contiguous readback + fully-coalesced NT stores. Wave touches only its
    // own LDS slice -> no __syncthreads needed.
    const vfloat4* lv = reinterpret_cast<const vfloat4*>(&lds[wave][0]);
    vfloat4* outv = reinterpret_cast<vfloat4*>(out);
    // Block writes 256 threads * 3 x 16B = 768 vfloat4; wave writes 192.
    const long base4 = (long)blockIdx.x * 768 + wave * 192;  // vfloat4 units
    #pragma unroll
    for (int j = 0; j < 3; ++j) {
        __builtin_nontemporal_store(lv[j * 64 + lane], &outv[base4 + j * 64 + lane]);
    }
}

extern "C" void kernel_launch(void* const* d_in, const int* in_sizes, int n_in,
                              void* d_out, int out_size, void* d_ws, size_t ws_size,
                              hipStream_t stream) {
    const float* depth = (const float*)d_in[0];
    const float* masks = (const float*)d_in[1];
    const float* intr  = (const float*)d_in[2];
    float* out = (float*)d_out;

    const int total_pixels = in_sizes[0];          // 16,777,216
    const int n_groups = total_pixels >> 2;        // 4,194,304 threads
    const int block = 256;
    const int grid = n_groups / block;             // 16,384 (exact)

    sam3d_pc_kernel<<<grid, block, 0, stream>>>(depth, masks, intr, out);
}